// Round 7
// baseline (56.731 us; speedup 1.0000x reference)
//
#include <hip/hip_runtime.h>
#include <cstdint>
#include <cstddef>

// Problem constants
#define NB    32
#define NC1   64
#define NC2   128
#define NE    4
#define NSLOT 5
#define HIN   64
#define WIN   64
#define HOUT  32
#define WOUT  32

// ws layout (float offsets)
#define GATEIN_OFF 0        // [32][64] f32
#define BIAS_OFF   2176     // [5][128] f32
#define GAMMA_OFF  2816     // [5][128] f32
#define BETA_OFF   3456     // [5][128] f32
#define WBF_OFF    4096     // bf16 frag table [5][9][4 wv][4 kk][64 lane][8]

typedef __bf16 bf16x8 __attribute__((ext_vector_type(8)));
typedef float  f32x16 __attribute__((ext_vector_type(16)));

#define GLOAD_LDS16(G, L)                                                        \
    __builtin_amdgcn_global_load_lds(                                            \
        (const __attribute__((address_space(1))) void*)(G),                      \
        (__attribute__((address_space(3))) void*)(L), 16, 0, 0)

// ---------------------------------------------------------------------------
// Kernel A (merged): blocks [0,1440): weight/bias repack into MFMA frag order
//   wfrag elem = slot*73728 + tap*8192 + wv*2048 + kk*512 + lane*8 + j
//     = W[slot][c2 = wv*32 + (lane&31)][c = kk*16 + (lane>>5)*8 + j][tap]
// blocks [1440,1952): gate_in[b][c] row means (one wave per (b,c) row).
// ---------------------------------------------------------------------------
__global__ void prep2_kernel(const float* __restrict__ x,
                             const float* __restrict__ expert_w,
                             const float* __restrict__ shared_w,
                             const float* __restrict__ expert_b,
                             const float* __restrict__ shared_b,
                             const float* __restrict__ eln_w,
                             const float* __restrict__ sln_w,
                             const float* __restrict__ eln_b,
                             const float* __restrict__ sln_b,
                             float* __restrict__ ws) {
    int bid = blockIdx.x;
    if (bid < 1440) {
        int i = bid * 256 + threadIdx.x;
        {
            int j    = i & 7;
            int l    = (i >> 3) & 63;
            int kk   = (i >> 9) & 3;
            int wv   = (i >> 11) & 3;
            int rest = i >> 13;
            int tap  = rest % 9;
            int e    = rest / 9;
            int c2 = wv * 32 + (l & 31);
            int c  = kk * 16 + (l >> 5) * 8 + j;
            float v;
            if (e < NE) v = expert_w[(((size_t)(e * NC2 + c2) * NC1 + c) * 9) + tap];
            else        v = shared_w[(((size_t)c2 * NC1 + c) * 9) + tap];
            ((__bf16*)(ws + WBF_OFF))[i] = (__bf16)v;
        }
        if (i < NSLOT * NC2) {
            int e = i >> 7, c2 = i & 127;
            ws[BIAS_OFF  + i] = (e < NE) ? expert_b[i] : shared_b[c2];
            ws[GAMMA_OFF + i] = (e < NE) ? eln_w[i]    : sln_w[c2];
            ws[BETA_OFF  + i] = (e < NE) ? eln_b[i]    : sln_b[c2];
        }
    } else {
        int row  = (bid - 1440) * 4 + (threadIdx.x >> 6);   // b*64 + c
        int lane = threadIdx.x & 63;
        const float* src = x + (size_t)row * (HIN * WIN);
        float s = 0.f;
        for (int i = lane * 4; i < HIN * WIN; i += 64 * 4) {
            float4 v = *(const float4*)(src + i);
            s += v.x + v.y + v.z + v.w;
        }
        #pragma unroll
        for (int off = 32; off >= 1; off >>= 1) s += __shfl_xor(s, off);
        if (lane == 0) ws[GATEIN_OFF + row] = s * (1.f / (HIN * WIN));
    }
}

// ---------------------------------------------------------------------------
// Kernel D: MFMA implicit-GEMM conv + LN + gated combine.
// Block = (b, hg), 256 threads = 4 waves (wv = c2 tile). Each wave owns
// 3 slots x 2 h' rows = 6 accumulators, and a PRIVATE 2-deep weight ring in
// LDS filled by its own global_load_lds chunks (12 x 1KB per tap). The 9-tap
// main loop has NO barriers: per tap only `s_waitcnt vmcnt(12)` (tap t
// resident, tap t+1 in flight) and `lgkmcnt(0)` before re-issuing into the
// ring slot just read. Waves drift freely -> DMA latency overlaps compute.
// LDS: xs 41600 | ring 4x24576 | red 6144  = 146048 B -> 1 block/CU.
// ---------------------------------------------------------------------------
#define XS_IDX(r, p, ps, c7) ((((r) * 65 + (p)) << 6) + ((ps) << 3) + (c7))
#define XS_BYTES   41600
#define RING_BYTES 98304
#define RING_WV    12288    // bf16 elems per wave (2 bufs x 12 chunks x 512)

__global__ __launch_bounds__(256, 1) void fused_kernel(
        const float* __restrict__ x,
        const float* __restrict__ w_gate,
        const float* __restrict__ ws,
        float* __restrict__ out) {
    __shared__ __align__(16) unsigned char smem[XS_BYTES + RING_BYTES + 6144];
    __bf16* xs   = (__bf16*)smem;
    __bf16* ring = (__bf16*)(smem + XS_BYTES);
    float*  red  = (float*)(smem + XS_BYTES + RING_BYTES);

    const int bid = blockIdx.x;             // 0..511
    const int b   = bid >> 4;
    const int hg  = bid & 15;
    const int tid = threadIdx.x;
    const int ln  = tid & 63;
    const int wv  = tid >> 6;               // wave 0..3 = c2 tile
    const int cl  = ln & 31;
    const int hl  = ln >> 5;
    const int wbase = wv * 32;

    // ---- gating: every wave computes top-2 softmax redundantly ----
    int s0, s1; float ga, gb;
    {
        float gi = ws[GATEIN_OFF + b * NC1 + ln];
        float l[NE];
        #pragma unroll
        for (int e = 0; e < NE; ++e) {
            float p = gi * w_gate[ln * NE + e];
            #pragma unroll
            for (int off = 32; off >= 1; off >>= 1) p += __shfl_xor(p, off);
            l[e] = p;
        }
        int i0 = 0; float v0 = l[0];
        #pragma unroll
        for (int e = 1; e < NE; ++e) if (l[e] > v0) { v0 = l[e]; i0 = e; }
        int i1 = -1; float v1 = -3.4e38f;
        #pragma unroll
        for (int e = 0; e < NE; ++e) if (e != i0 && l[e] > v1) { v1 = l[e]; i1 = e; }
        float e1 = expf(v1 - v0);
        float denom = 1.f + e1;
        s0 = i0; ga = 1.f / denom;
        s1 = i1; gb = e1 / denom;
    }

    // ---- x stage: 5 rows (hin = 4hg-1+r), transpose+bf16, swizzled ----
    for (int idx = tid; idx < 5 * 1024; idx += 256) {
        int r   = idx >> 10;
        int rem = idx & 1023;
        int c   = rem >> 4;
        int i4  = rem & 15;
        int hin = 4 * hg - 1 + r;
        float4 v = make_float4(0.f, 0.f, 0.f, 0.f);
        if (hin >= 0)
            v = *(const float4*)(x + (((size_t)b * NC1 + c) * HIN + hin) * WIN + i4 * 4);
        #pragma unroll
        for (int k = 0; k < 4; ++k) {
            int p  = i4 * 4 + k + 1;
            int ps = (c >> 3) ^ ((p >> 1) & 7);
            float f = (k == 0) ? v.x : (k == 1) ? v.y : (k == 2) ? v.z : v.w;
            xs[XS_IDX(r, p, ps, c & 7)] = (__bf16)f;
        }
    }
    if (tid < 64) {   // zero left-pad column p=0
        #pragma unroll
        for (int r = 0; r < 5; ++r) xs[XS_IDX(r, 0, (tid >> 3), tid & 7)] = (__bf16)0.f;
    }

    // ---- init 6 accumulators with bias (same bias for both h' rows) ----
    const int rowbase = wbase + 4 * hl;
    f32x16 a00, a01, a10, a11, a20, a21;
    #define INIT_ACC(ACC, SID)                                                  \
    {                                                                           \
        const float4* bp = (const float4*)(ws + BIAS_OFF + (SID) * NC2 + rowbase); \
        float4 b0 = bp[0], b1 = bp[2], b2 = bp[4], b3 = bp[6];                  \
        ACC[0]=b0.x; ACC[1]=b0.y; ACC[2]=b0.z; ACC[3]=b0.w;                     \
        ACC[4]=b1.x; ACC[5]=b1.y; ACC[6]=b1.z; ACC[7]=b1.w;                     \
        ACC[8]=b2.x; ACC[9]=b2.y; ACC[10]=b2.z; ACC[11]=b2.w;                   \
        ACC[12]=b3.x; ACC[13]=b3.y; ACC[14]=b3.z; ACC[15]=b3.w;                 \
    }
    INIT_ACC(a00, s0) a01 = a00;
    INIT_ACC(a10, s1) a11 = a10;
    INIT_ACC(a20, 4)  a21 = a20;

    __syncthreads();   // xs published; vmcnt fully drained by syncthreads

    // ---- wave-private weight DMA: 12 chunks of 1KB per tap ----
    const __bf16* wtab = (const __bf16*)(ws + WBF_OFF);
    #define ISSUE_W(TAP, BUF)                                                     \
    {                                                                             \
        _Pragma("unroll")                                                         \
        for (int ch = 0; ch < 12; ++ch) {                                         \
            int si = ch >> 2, kk = ch & 3;                                        \
            int sl = (si == 0) ? s0 : ((si == 1) ? s1 : 4);                       \
            const __bf16* g = wtab + (size_t)sl * 73728 + (TAP) * 8192            \
                              + wv * 2048 + kk * 512 + ln * 8;                    \
            __bf16* d = ring + wv * RING_WV + (BUF) * 6144 + ch * 512;            \
            GLOAD_LDS16(g, d);                                                    \
        }                                                                         \
    }
    ISSUE_W(0, 0)
    ISSUE_W(1, 1)

    // ---- main loop: 9 taps, barrier-free, counted vmcnt ----
    #define MFMA(A, B, C) C = __builtin_amdgcn_mfma_f32_32x32x16_bf16(A, B, C, 0, 0, 0)
    const int p_l = 2 * cl;
    #pragma unroll
    for (int t = 0; t < 9; ++t) {
        if (t < 8) { asm volatile("s_waitcnt vmcnt(12)" ::: "memory"); }
        else       { asm volatile("s_waitcnt vmcnt(0)"  ::: "memory"); }

        const int r3  = t / 3;
        const int kw  = t % 3;
        const int p   = p_l + kw;
        const int swb = (p >> 1) & 7;
        const __bf16* rb = ring + wv * RING_WV + (t & 1) * 6144 + ln * 8;

        bf16x8 bA0 = *(const bf16x8*)&xs[XS_IDX(r3,     p, (0 + hl) ^ swb, 0)];
        bf16x8 bA1 = *(const bf16x8*)&xs[XS_IDX(r3,     p, (2 + hl) ^ swb, 0)];
        bf16x8 bA2 = *(const bf16x8*)&xs[XS_IDX(r3,     p, (4 + hl) ^ swb, 0)];
        bf16x8 bA3 = *(const bf16x8*)&xs[XS_IDX(r3,     p, (6 + hl) ^ swb, 0)];
        bf16x8 bB0 = *(const bf16x8*)&xs[XS_IDX(r3 + 2, p, (0 + hl) ^ swb, 0)];
        bf16x8 bB1 = *(const bf16x8*)&xs[XS_IDX(r3 + 2, p, (2 + hl) ^ swb, 0)];
        bf16x8 bB2 = *(const bf16x8*)&xs[XS_IDX(r3 + 2, p, (4 + hl) ^ swb, 0)];
        bf16x8 bB3 = *(const bf16x8*)&xs[XS_IDX(r3 + 2, p, (6 + hl) ^ swb, 0)];

        bf16x8 v;
        v = *(const bf16x8*)(rb + 0  * 512); MFMA(v, bA0, a00); MFMA(v, bB0, a01);
        v = *(const bf16x8*)(rb + 1  * 512); MFMA(v, bA1, a00); MFMA(v, bB1, a01);
        v = *(const bf16x8*)(rb + 2  * 512); MFMA(v, bA2, a00); MFMA(v, bB2, a01);
        v = *(const bf16x8*)(rb + 3  * 512); MFMA(v, bA3, a00); MFMA(v, bB3, a01);
        v = *(const bf16x8*)(rb + 4  * 512); MFMA(v, bA0, a10); MFMA(v, bB0, a11);
        v = *(const bf16x8*)(rb + 5  * 512); MFMA(v, bA1, a10); MFMA(v, bB1, a11);
        v = *(const bf16x8*)(rb + 6  * 512); MFMA(v, bA2, a10); MFMA(v, bB2, a11);
        v = *(const bf16x8*)(rb + 7  * 512); MFMA(v, bA3, a10); MFMA(v, bB3, a11);
        v = *(const bf16x8*)(rb + 8  * 512); MFMA(v, bA0, a20); MFMA(v, bB0, a21);
        v = *(const bf16x8*)(rb + 9  * 512); MFMA(v, bA1, a20); MFMA(v, bB1, a21);
        v = *(const bf16x8*)(rb + 10 * 512); MFMA(v, bA2, a20); MFMA(v, bB2, a21);
        v = *(const bf16x8*)(rb + 11 * 512); MFMA(v, bA3, a20); MFMA(v, bB3, a21);

        // ring slot (t&1) fully consumed (data returned) before re-issue:
        asm volatile("s_waitcnt lgkmcnt(0)" ::: "memory");
        if (t < 7) { ISSUE_W(t + 2, (t & 1)) }
    }

    // ---- LN partials: red[((si*2+tg)*2+stat)*128 + c2col] ----
    #define PUT_RED(ACC, SI, TG)                                                  \
    {                                                                             \
        float sum = 0.f, sq = 0.f;                                                \
        _Pragma("unroll")                                                         \
        for (int i = 0; i < 16; ++i) { float a = ACC[i]; sum += a; sq += a * a; } \
        sum += __shfl_xor(sum, 32); sq += __shfl_xor(sq, 32);                     \
        if (ln < 32) {                                                            \
            red[(((SI) * 2 + (TG)) * 2 + 0) * 128 + wbase + cl] = sum;            \
            red[(((SI) * 2 + (TG)) * 2 + 1) * 128 + wbase + cl] = sq;             \
        }                                                                         \
    }
    PUT_RED(a00, 0, 0) PUT_RED(a01, 0, 1)
    PUT_RED(a10, 1, 0) PUT_RED(a11, 1, 1)
    PUT_RED(a20, 2, 0) PUT_RED(a21, 2, 1)
    __syncthreads();

    float fin0[16], fin1[16];
    #pragma unroll
    for (int i = 0; i < 16; ++i) { fin0[i] = 0.f; fin1[i] = 0.f; }

    #define APPLY(ACC, FIN, SI, TG, GM, BT, G)                                    \
    {                                                                             \
        float tot = 0.f, totq = 0.f;                                              \
        _Pragma("unroll")                                                         \
        for (int w = 0; w < 4; ++w) {                                             \
            tot  += red[(((SI) * 2 + (TG)) * 2 + 0) * 128 + w * 32 + cl];         \
            totq += red[(((SI) * 2 + (TG)) * 2 + 1) * 128 + w * 32 + cl];         \
        }                                                                         \
        float mean = tot * (1.f / NC2);                                           \
        float var  = totq * (1.f / NC2) - mean * mean;                            \
        float rstd = rsqrtf(var + 1e-6f);                                         \
        _Pragma("unroll")                                                         \
        for (int i = 0; i < 16; ++i) {                                            \
            float nrm = (ACC[i] - mean) * rstd;                                   \
            FIN[i] = fmaf((G), fmaf(GM[i], nrm, BT[i]), FIN[i]);                  \
        }                                                                         \
    }
    #define LOAD_GB(SID, GM, BT)                                                  \
        float GM[16], BT[16];                                                     \
        {                                                                         \
            const float4* gmp = (const float4*)(ws + GAMMA_OFF + (SID) * NC2 + rowbase); \
            const float4* btp = (const float4*)(ws + BETA_OFF  + (SID) * NC2 + rowbase); \
            float4 g0 = gmp[0], g1 = gmp[2], g2 = gmp[4], g3 = gmp[6];            \
            float4 t0 = btp[0], t1 = btp[2], t2 = btp[4], t3 = btp[6];            \
            GM[0]=g0.x;GM[1]=g0.y;GM[2]=g0.z;GM[3]=g0.w;GM[4]=g1.x;GM[5]=g1.y;GM[6]=g1.z;GM[7]=g1.w; \
            GM[8]=g2.x;GM[9]=g2.y;GM[10]=g2.z;GM[11]=g2.w;GM[12]=g3.x;GM[13]=g3.y;GM[14]=g3.z;GM[15]=g3.w; \
            BT[0]=t0.x;BT[1]=t0.y;BT[2]=t0.z;BT[3]=t0.w;BT[4]=t1.x;BT[5]=t1.y;BT[6]=t1.z;BT[7]=t1.w; \
            BT[8]=t2.x;BT[9]=t2.y;BT[10]=t2.z;BT[11]=t2.w;BT[12]=t3.x;BT[13]=t3.y;BT[14]=t3.z;BT[15]=t3.w; \
        }
    {
        LOAD_GB(s0, gm0, bt0)
        APPLY(a00, fin0, 0, 0, gm0, bt0, ga)
        APPLY(a01, fin1, 0, 1, gm0, bt0, ga)
    }
    {
        LOAD_GB(s1, gm1, bt1)
        APPLY(a10, fin0, 1, 0, gm1, bt1, gb)
        APPLY(a11, fin1, 1, 1, gm1, bt1, gb)
    }
    {
        LOAD_GB(4, gm2, bt2)
        APPLY(a20, fin0, 2, 0, gm2, bt2, 1.0f)
        APPLY(a21, fin1, 2, 1, gm2, bt2, 1.0f)
    }

    // ---- out-tile in LDS (aliases dead ring region), coalesced store ----
    float* ob = (float*)(smem + XS_BYTES);   // [tg][128 c2][32 w'] = 32768 B
    #pragma unroll
    for (int i = 0; i < 16; ++i) {
        int c2 = rowbase + (i & 3) + 8 * (i >> 2);
        ob[(0 * 128 + c2) * 32 + cl] = fin0[i];
        ob[(1 * 128 + c2) * 32 + cl] = fin1[i];
    }
    __syncthreads();
    for (int idx = tid; idx < 2048; idx += 256) {
        int t2  = idx >> 10;
        int rem = idx & 1023;
        int c2  = rem >> 3;
        int q   = rem & 7;
        float4 v = *(const float4*)&ob[(t2 * 128 + c2) * 32 + q * 4];
        *(float4*)(out + (((size_t)b * NC2 + c2) * HOUT + 2 * hg + t2) * WOUT + q * 4) = v;
    }
}

// ---------------------------------------------------------------------------
extern "C" void kernel_launch(void* const* d_in, const int* in_sizes, int n_in,
                              void* d_out, int out_size, void* d_ws, size_t ws_size,
                              hipStream_t stream) {
    const float* x        = (const float*)d_in[0];
    const float* w_gate   = (const float*)d_in[1];
    const float* expert_w = (const float*)d_in[2];
    const float* expert_b = (const float*)d_in[3];
    const float* eln_w    = (const float*)d_in[4];
    const float* eln_b    = (const float*)d_in[5];
    const float* shared_w = (const float*)d_in[6];
    const float* shared_b = (const float*)d_in[7];
    const float* sln_w    = (const float*)d_in[8];
    const float* sln_b    = (const float*)d_in[9];
    float* ws  = (float*)d_ws;
    float* out = (float*)d_out;

    prep2_kernel<<<1952, 256, 0, stream>>>(x, expert_w, shared_w, expert_b, shared_b,
                                           eln_w, sln_w, eln_b, sln_b, ws);
    fused_kernel<<<NB * 16, 256, 0, stream>>>(x, w_gate, ws, out);
}

// Round 8
// 39.136 us; speedup vs baseline: 1.4496x; 1.4496x over previous
//
#include <hip/hip_runtime.h>
#include <cstdint>
#include <cstddef>

// Problem constants
#define NB    32
#define NC1   64
#define NC2   128
#define NE    4
#define NSLOT 5
#define HIN   64
#define WIN   64
#define HOUT  32
#define WOUT  32

// ws layout (float offsets)
#define GATEIN_OFF 0        // [32][64] f32
#define BIAS_OFF   2176     // [5][128] f32
#define GAMMA_OFF  2816     // [5][128] f32
#define BETA_OFF   3456     // [5][128] f32
#define WBF_OFF    4096     // bf16 frag table [5][9][4 wv][4 kk][64 lane][8]

typedef __bf16 bf16x8 __attribute__((ext_vector_type(8)));
typedef float  f32x16 __attribute__((ext_vector_type(16)));

// ---------------------------------------------------------------------------
// Kernel A (merged): blocks [0,1440): weight/bias repack into MFMA frag order
//   wfrag elem = slot*73728 + tap*8192 + wv*2048 + kk*512 + lane*8 + j
//     = W[slot][c2 = wv*32 + (lane&31)][c = kk*16 + (lane>>5)*8 + j][tap]
// blocks [1440,1952): gate_in[b][c] row means (one wave per (b,c) row).
// ---------------------------------------------------------------------------
__global__ void prep2_kernel(const float* __restrict__ x,
                             const float* __restrict__ expert_w,
                             const float* __restrict__ shared_w,
                             const float* __restrict__ expert_b,
                             const float* __restrict__ shared_b,
                             const float* __restrict__ eln_w,
                             const float* __restrict__ sln_w,
                             const float* __restrict__ eln_b,
                             const float* __restrict__ sln_b,
                             float* __restrict__ ws) {
    int bid = blockIdx.x;
    if (bid < 1440) {
        int i = bid * 256 + threadIdx.x;
        {
            int j    = i & 7;
            int l    = (i >> 3) & 63;
            int kk   = (i >> 9) & 3;
            int wv   = (i >> 11) & 3;
            int rest = i >> 13;
            int tap  = rest % 9;
            int e    = rest / 9;
            int c2 = wv * 32 + (l & 31);
            int c  = kk * 16 + (l >> 5) * 8 + j;
            float v;
            if (e < NE) v = expert_w[(((size_t)(e * NC2 + c2) * NC1 + c) * 9) + tap];
            else        v = shared_w[(((size_t)c2 * NC1 + c) * 9) + tap];
            ((__bf16*)(ws + WBF_OFF))[i] = (__bf16)v;
        }
        if (i < NSLOT * NC2) {
            int e = i >> 7, c2 = i & 127;
            ws[BIAS_OFF  + i] = (e < NE) ? expert_b[i] : shared_b[c2];
            ws[GAMMA_OFF + i] = (e < NE) ? eln_w[i]    : sln_w[c2];
            ws[BETA_OFF  + i] = (e < NE) ? eln_b[i]    : sln_b[c2];
        }
    } else {
        int row  = (bid - 1440) * 4 + (threadIdx.x >> 6);   // b*64 + c
        int lane = threadIdx.x & 63;
        const float* src = x + (size_t)row * (HIN * WIN);
        float s = 0.f;
        for (int i = lane * 4; i < HIN * WIN; i += 64 * 4) {
            float4 v = *(const float4*)(src + i);
            s += v.x + v.y + v.z + v.w;
        }
        #pragma unroll
        for (int off = 32; off >= 1; off >>= 1) s += __shfl_xor(s, off);
        if (lane == 0) ws[GATEIN_OFF + row] = s * (1.f / (HIN * WIN));
    }
}

// ---------------------------------------------------------------------------
// Kernel D: MFMA implicit-GEMM conv + LN + gated combine.
// Block = (b, q), q in 0..7 -> h' rows 4q..4q+3. Grid = 256 = 1 block/CU.
// 512 thr = 8 waves: (tg in {0,1} -> h' rows {4q+2tg, 4q+2tg+1}), wv = c2 tile.
// Each wave: 3 slots x 2 h' rows = 6 accumulators (96 regs).
// Weights: direct per-wave VGPR loads from the frag table, explicitly
// double-buffered in registers (A0/A1 ping-pong, fully unrolled so all
// indices are static). NO barriers in the 9-tap loop; 256-reg budget via
// __launch_bounds__(512,2) leaves room for the 96-reg prefetch.
// LDS: xs 9x65x64 bf16 = 74880 B | red 12288 B = 87168 B.
// ---------------------------------------------------------------------------
#define XS_IDX(r, p, ps, c7) ((((r) * 65 + (p)) << 6) + ((ps) << 3) + (c7))

__global__ __launch_bounds__(512, 2) void fused_kernel(
        const float* __restrict__ x,
        const float* __restrict__ w_gate,
        const float* __restrict__ ws,
        float* __restrict__ out) {
    __shared__ __bf16 xs[9 * 65 * 64];          // 74880 B
    __shared__ float  red[3 * 2 * 2 * 2 * 128]; // [si][tg][u][stat][128] 12288 B

    const int bid = blockIdx.x;             // 0..255
    const int b   = bid >> 3;
    const int q   = bid & 7;                // h' quad = 4q..4q+3
    const int tid = threadIdx.x;
    const int ln  = tid & 63;
    const int wv8 = tid >> 6;               // 0..7
    const int tg  = wv8 >> 2;               // h'-pair within quad
    const int wv  = wv8 & 3;                // c2 tile
    const int cl  = ln & 31;
    const int hl  = ln >> 5;
    const int wbase = wv * 32;

    // ---- gating: every wave computes top-2 softmax redundantly ----
    int s0, s1; float ga, gb;
    {
        float gi = ws[GATEIN_OFF + b * NC1 + ln];
        float l[NE];
        #pragma unroll
        for (int e = 0; e < NE; ++e) {
            float p = gi * w_gate[ln * NE + e];
            #pragma unroll
            for (int off = 32; off >= 1; off >>= 1) p += __shfl_xor(p, off);
            l[e] = p;
        }
        int i0 = 0; float v0 = l[0];
        #pragma unroll
        for (int e = 1; e < NE; ++e) if (l[e] > v0) { v0 = l[e]; i0 = e; }
        int i1 = -1; float v1 = -3.4e38f;
        #pragma unroll
        for (int e = 0; e < NE; ++e) if (e != i0 && l[e] > v1) { v1 = l[e]; i1 = e; }
        float e1 = expf(v1 - v0);
        float denom = 1.f + e1;
        s0 = i0; ga = 1.f / denom;
        s1 = i1; gb = e1 / denom;
    }

    // ---- A-frag base pointers (contiguous 1KB per wave per load) ----
    const __bf16* wtab = (const __bf16*)(ws + WBF_OFF);
    const __bf16* ap0 = wtab + (size_t)s0 * 73728 + wv * 2048 + ln * 8;
    const __bf16* ap1 = wtab + (size_t)s1 * 73728 + wv * 2048 + ln * 8;
    const __bf16* ap2 = wtab + (size_t)4  * 73728 + wv * 2048 + ln * 8;

    bf16x8 A0[12], A1[12];
    #define LOAD_A(DST, TAP)                                                      \
    {                                                                             \
        _Pragma("unroll")                                                         \
        for (int kk = 0; kk < 4; ++kk) {                                          \
            DST[kk]     = *(const bf16x8*)(ap0 + (TAP) * 8192 + kk * 512);        \
            DST[4 + kk] = *(const bf16x8*)(ap1 + (TAP) * 8192 + kk * 512);        \
            DST[8 + kk] = *(const bf16x8*)(ap2 + (TAP) * 8192 + kk * 512);        \
        }                                                                         \
    }
    LOAD_A(A0, 0)   // tap-0 frags fly while we stage x

    // ---- x stage: 9 rows (hin = 8q-1+r), transpose+bf16, swizzled ----
    #pragma unroll
    for (int pass = 0; pass < 18; ++pass) {
        int idx = pass * 512 + tid;         // 0..9215
        int r   = idx >> 10;
        int rem = idx & 1023;
        int c   = rem >> 4;
        int i4  = rem & 15;
        int hin = 8 * q - 1 + r;
        float4 v = make_float4(0.f, 0.f, 0.f, 0.f);
        if (hin >= 0)
            v = *(const float4*)(x + (((size_t)b * NC1 + c) * HIN + hin) * WIN + i4 * 4);
        #pragma unroll
        for (int k = 0; k < 4; ++k) {
            int p  = i4 * 4 + k + 1;
            int ps = (c >> 3) ^ ((p >> 1) & 7);
            float f = (k == 0) ? v.x : (k == 1) ? v.y : (k == 2) ? v.z : v.w;
            xs[XS_IDX(r, p, ps, c & 7)] = (__bf16)f;
        }
    }
    if (tid < 64) {   // zero left-pad column p=0 for all 9 rows
        #pragma unroll
        for (int r = 0; r < 9; ++r) xs[XS_IDX(r, 0, (tid >> 3), tid & 7)] = (__bf16)0.f;
    }

    // ---- init 6 accumulators with bias ----
    const int rowbase = wbase + 4 * hl;
    f32x16 c00, c01, c10, c11, c20, c21;
    #define INIT_ACC(ACC, SID)                                                  \
    {                                                                           \
        const float4* bp = (const float4*)(ws + BIAS_OFF + (SID) * NC2 + rowbase); \
        float4 b0 = bp[0], b1 = bp[2], b2 = bp[4], b3 = bp[6];                  \
        ACC[0]=b0.x; ACC[1]=b0.y; ACC[2]=b0.z; ACC[3]=b0.w;                     \
        ACC[4]=b1.x; ACC[5]=b1.y; ACC[6]=b1.z; ACC[7]=b1.w;                     \
        ACC[8]=b2.x; ACC[9]=b2.y; ACC[10]=b2.z; ACC[11]=b2.w;                   \
        ACC[12]=b3.x; ACC[13]=b3.y; ACC[14]=b3.z; ACC[15]=b3.w;                 \
    }
    INIT_ACC(c00, s0) c01 = c00;
    INIT_ACC(c10, s1) c11 = c10;
    INIT_ACC(c20, 4)  c21 = c20;

    __syncthreads();   // xs published (also drains A0 loads)

    // ---- 9-tap main loop: barrier-free, register ping-pong A0/A1 ----
    #define MFMA(A, B, C) C = __builtin_amdgcn_mfma_f32_32x32x16_bf16(A, B, C, 0, 0, 0)
    const int p_l = 2 * cl;
    #define COMPUTE(A, TAP)                                                       \
    {                                                                             \
        const int r3  = (TAP) / 3;                                                \
        const int kw  = (TAP) % 3;                                                \
        const int p   = p_l + kw;                                                 \
        const int swb = (p >> 1) & 7;                                             \
        const int rA  = 4 * tg + r3;                                              \
        const int rB  = rA + 2;                                                   \
        bf16x8 bA0 = *(const bf16x8*)&xs[XS_IDX(rA, p, (0 + hl) ^ swb, 0)];       \
        bf16x8 bA1 = *(const bf16x8*)&xs[XS_IDX(rA, p, (2 + hl) ^ swb, 0)];       \
        bf16x8 bA2 = *(const bf16x8*)&xs[XS_IDX(rA, p, (4 + hl) ^ swb, 0)];       \
        bf16x8 bA3 = *(const bf16x8*)&xs[XS_IDX(rA, p, (6 + hl) ^ swb, 0)];       \
        bf16x8 bB0 = *(const bf16x8*)&xs[XS_IDX(rB, p, (0 + hl) ^ swb, 0)];       \
        bf16x8 bB1 = *(const bf16x8*)&xs[XS_IDX(rB, p, (2 + hl) ^ swb, 0)];       \
        bf16x8 bB2 = *(const bf16x8*)&xs[XS_IDX(rB, p, (4 + hl) ^ swb, 0)];       \
        bf16x8 bB3 = *(const bf16x8*)&xs[XS_IDX(rB, p, (6 + hl) ^ swb, 0)];       \
        MFMA(A[0], bA0, c00); MFMA(A[0], bB0, c01);                               \
        MFMA(A[1], bA1, c00); MFMA(A[1], bB1, c01);                               \
        MFMA(A[2], bA2, c00); MFMA(A[2], bB2, c01);                               \
        MFMA(A[3], bA3, c00); MFMA(A[3], bB3, c01);                               \
        MFMA(A[4], bA0, c10); MFMA(A[4], bB0, c11);                               \
        MFMA(A[5], bA1, c10); MFMA(A[5], bB1, c11);                               \
        MFMA(A[6], bA2, c10); MFMA(A[6], bB2, c11);                               \
        MFMA(A[7], bA3, c10); MFMA(A[7], bB3, c11);                               \
        MFMA(A[8], bA0, c20); MFMA(A[8], bB0, c21);                               \
        MFMA(A[9], bA1, c20); MFMA(A[9], bB1, c21);                               \
        MFMA(A[10], bA2, c20); MFMA(A[10], bB2, c21);                             \
        MFMA(A[11], bA3, c20); MFMA(A[11], bB3, c21);                             \
    }
    LOAD_A(A1, 1)  COMPUTE(A0, 0)  LOAD_A(A0, 2)  COMPUTE(A1, 1)
    LOAD_A(A1, 3)  COMPUTE(A0, 2)  LOAD_A(A0, 4)  COMPUTE(A1, 3)
    LOAD_A(A1, 5)  COMPUTE(A0, 4)  LOAD_A(A0, 6)  COMPUTE(A1, 5)
    LOAD_A(A1, 7)  COMPUTE(A0, 6)  LOAD_A(A0, 8)  COMPUTE(A1, 7)
    COMPUTE(A0, 8)

    // ---- LN partials: red[(((si*2+tg)*2+u)*2+stat)*128 + col] ----
    #define PUT_RED(ACC, SI, U)                                                   \
    {                                                                             \
        float sum = 0.f, sq = 0.f;                                                \
        _Pragma("unroll")                                                         \
        for (int i = 0; i < 16; ++i) { float a = ACC[i]; sum += a; sq += a * a; } \
        sum += __shfl_xor(sum, 32); sq += __shfl_xor(sq, 32);                     \
        if (ln < 32) {                                                            \
            red[((((SI) * 2 + tg) * 2 + (U)) * 2 + 0) * 128 + wbase + cl] = sum;  \
            red[((((SI) * 2 + tg) * 2 + (U)) * 2 + 1) * 128 + wbase + cl] = sq;   \
        }                                                                         \
    }
    PUT_RED(c00, 0, 0) PUT_RED(c01, 0, 1)
    PUT_RED(c10, 1, 0) PUT_RED(c11, 1, 1)
    PUT_RED(c20, 2, 0) PUT_RED(c21, 2, 1)
    __syncthreads();

    float fin0[16], fin1[16];
    #pragma unroll
    for (int i = 0; i < 16; ++i) { fin0[i] = 0.f; fin1[i] = 0.f; }

    #define APPLY(ACC, FIN, SI, U, GM, BT, G)                                     \
    {                                                                             \
        float tot = 0.f, totq = 0.f;                                              \
        _Pragma("unroll")                                                         \
        for (int w = 0; w < 4; ++w) {                                             \
            tot  += red[((((SI) * 2 + tg) * 2 + (U)) * 2 + 0) * 128 + w * 32 + cl]; \
            totq += red[((((SI) * 2 + tg) * 2 + (U)) * 2 + 1) * 128 + w * 32 + cl]; \
        }                                                                         \
        float mean = tot * (1.f / NC2);                                           \
        float var  = totq * (1.f / NC2) - mean * mean;                            \
        float rstd = rsqrtf(var + 1e-6f);                                         \
        _Pragma("unroll")                                                         \
        for (int i = 0; i < 16; ++i) {                                            \
            float nrm = (ACC[i] - mean) * rstd;                                   \
            FIN[i] = fmaf((G), fmaf(GM[i], nrm, BT[i]), FIN[i]);                  \
        }                                                                         \
    }
    #define LOAD_GB(SID, GM, BT)                                                  \
        float GM[16], BT[16];                                                     \
        {                                                                         \
            const float4* gmp = (const float4*)(ws + GAMMA_OFF + (SID) * NC2 + rowbase); \
            const float4* btp = (const float4*)(ws + BETA_OFF  + (SID) * NC2 + rowbase); \
            float4 g0 = gmp[0], g1 = gmp[2], g2 = gmp[4], g3 = gmp[6];            \
            float4 t0 = btp[0], t1 = btp[2], t2 = btp[4], t3 = btp[6];            \
            GM[0]=g0.x;GM[1]=g0.y;GM[2]=g0.z;GM[3]=g0.w;GM[4]=g1.x;GM[5]=g1.y;GM[6]=g1.z;GM[7]=g1.w; \
            GM[8]=g2.x;GM[9]=g2.y;GM[10]=g2.z;GM[11]=g2.w;GM[12]=g3.x;GM[13]=g3.y;GM[14]=g3.z;GM[15]=g3.w; \
            BT[0]=t0.x;BT[1]=t0.y;BT[2]=t0.z;BT[3]=t0.w;BT[4]=t1.x;BT[5]=t1.y;BT[6]=t1.z;BT[7]=t1.w; \
            BT[8]=t2.x;BT[9]=t2.y;BT[10]=t2.z;BT[11]=t2.w;BT[12]=t3.x;BT[13]=t3.y;BT[14]=t3.z;BT[15]=t3.w; \
        }
    {
        LOAD_GB(s0, gm0, bt0)
        APPLY(c00, fin0, 0, 0, gm0, bt0, ga)
        APPLY(c01, fin1, 0, 1, gm0, bt0, ga)
    }
    {
        LOAD_GB(s1, gm1, bt1)
        APPLY(c10, fin0, 1, 0, gm1, bt1, gb)
        APPLY(c11, fin1, 1, 1, gm1, bt1, gb)
    }
    {
        LOAD_GB(4, gm2, bt2)
        APPLY(c20, fin0, 2, 0, gm2, bt2, 1.0f)
        APPLY(c21, fin1, 2, 1, gm2, bt2, 1.0f)
    }

    // ---- store 2 h' rows per wave ----
    {
        const int hp0 = 4 * q + 2 * tg;
        float* ob = out + (size_t)b * (NC2 * HOUT * WOUT) + hp0 * WOUT + cl;
        #pragma unroll
        for (int i = 0; i < 16; ++i) {
            int c2 = rowbase + (i & 3) + 8 * (i >> 2);
            ob[(size_t)c2 * (HOUT * WOUT)] = fin0[i];
            ob[(size_t)c2 * (HOUT * WOUT) + WOUT] = fin1[i];
        }
    }
}

// ---------------------------------------------------------------------------
extern "C" void kernel_launch(void* const* d_in, const int* in_sizes, int n_in,
                              void* d_out, int out_size, void* d_ws, size_t ws_size,
                              hipStream_t stream) {
    const float* x        = (const float*)d_in[0];
    const float* w_gate   = (const float*)d_in[1];
    const float* expert_w = (const float*)d_in[2];
    const float* expert_b = (const float*)d_in[3];
    const float* eln_w    = (const float*)d_in[4];
    const float* eln_b    = (const float*)d_in[5];
    const float* shared_w = (const float*)d_in[6];
    const float* shared_b = (const float*)d_in[7];
    const float* sln_w    = (const float*)d_in[8];
    const float* sln_b    = (const float*)d_in[9];
    float* ws  = (float*)d_ws;
    float* out = (float*)d_out;

    prep2_kernel<<<1952, 256, 0, stream>>>(x, expert_w, shared_w, expert_b, shared_b,
                                           eln_w, sln_w, eln_b, sln_b, ws);
    fused_kernel<<<NB * 8, 512, 0, stream>>>(x, w_gate, ws, out);
}